// Round 5
// baseline (7781.609 us; speedup 1.0000x reference)
//
#include <hip/hip_runtime.h>
#include <cstdint>

typedef __attribute__((ext_vector_type(8))) short bf16x8;
typedef __attribute__((ext_vector_type(4))) float f32x4;
typedef __attribute__((ext_vector_type(2))) int i32x2;

__device__ __forceinline__ float bf2f(unsigned short u) {
  union { unsigned int i; float f; } v;
  v.i = ((unsigned int)u) << 16;
  return v.f;
}
__device__ __forceinline__ unsigned short f2bf(float f) {
  union { float f; unsigned int i; } v;
  v.f = f;
  unsigned int x = v.i;
  return (unsigned short)((x + 0x7FFFu + ((x >> 16) & 1u)) >> 16);
}

// ---- coherent (write-through to MALL) stores for cross-XCD mutable data ----
__device__ __forceinline__ void st_f32_coh(float* p, float v) {
  asm volatile("global_store_dword %0, %1, off sc0 sc1" :: "v"(p), "v"(v) : "memory");
}
__device__ __forceinline__ void st_u16_coh(unsigned short* p, unsigned int v) {
  asm volatile("global_store_short %0, %1, off sc0 sc1" :: "v"(p), "v"(v) : "memory");
}
__device__ __forceinline__ void st_b64_coh(void* p, i32x2 v) {
  asm volatile("global_store_dwordx2 %0, %1, off sc0 sc1" :: "v"(p), "v"(v) : "memory");
}

struct StepParams {
  const int* tgt;
  const int* mask;
  const float* embedding;
  const float* enc;
  const float* Wa;
  const float* hidden;
  const float* w_ih0; const float* w_hh0; const float* b_ih0; const float* b_hh0;
  const float* w_ih1; const float* w_hh1; const float* b_ih1; const float* b_hh1;
  float* h0buf;              // [64][32][512] rotating slots
  float* h1buf;              // [64][32][512] rotating slots
  float* x0b;                // [63][32][1536] rotating slots
  unsigned short* encb;      // [32][128][1024] bf16
  unsigned short* encwt;     // [32][128][512] bf16  (TRANSPOSED: [b][s][h])
  unsigned short* states;    // [2048][1536] bf16
  unsigned int* bars;        // one counter per barrier instance, pre-zeroed
};

// Pure-atomic grid barrier (round-3 verified): producers write shared mutable
// data sc0sc1 write-through (lands at MALL, no dirty L2), every mutable slot is
// renamed per step (consumer first-touch -> no stale L1/L2 copy). Weights/enc
// tables stay in L2 across the whole kernel; no fences, no invalidates.
__device__ __forceinline__ void gbar(unsigned int* c) {
  asm volatile("s_waitcnt vmcnt(0)" ::: "memory");  // drain this wave's coh stores
  __syncthreads();
  if (threadIdx.x == 0) {
    __hip_atomic_fetch_add(c, 1u, __ATOMIC_RELAXED, __HIP_MEMORY_SCOPE_AGENT);
    while (__hip_atomic_load(c, __ATOMIC_RELAXED, __HIP_MEMORY_SCOPE_AGENT) < 256u)
      __builtin_amdgcn_s_sleep(1);
  }
  __syncthreads();
}

// One GRU layer phase, 512 threads. tid = kq*64 + jl*32 + b (kq in [0,8));
// wg owns features j = w*2 + jl. 8-way k-split, 8-partial LDS reduction.
__device__ __forceinline__ void gru_phase(
    const float* __restrict__ x, int xK,
    const float* __restrict__ hprev,
    const float* __restrict__ w_ih, const float* __restrict__ w_hh,
    const float* __restrict__ b_ih, const float* __restrict__ b_hh,
    float* __restrict__ hout, unsigned short* states, int srow,
    int w, int tid, float* xsh, float* red) {
  int b = tid & 31;
  int jl = (tid >> 5) & 1;
  int kq = tid >> 6;          // 0..7
  int j = w * 2 + jl;
  int kb = kq * 32;
  float gr = 0.f, gz = 0.f, gin = 0.f, ghn = 0.f;
  for (int t0 = 0; t0 < xK; t0 += 256) {
    __syncthreads();
#pragma unroll
    for (int u = 0; u < 16; u++) {  // stage [32][256] chunk, lane-stride-1
      int idx = u * 512 + tid;
      xsh[(idx >> 8) * 257 + (idx & 255)] =
          x[(size_t)(idx >> 8) * xK + t0 + (idx & 255)];
    }
    __syncthreads();
    const float4* w0p = (const float4*)(w_ih + (size_t)j * xK + t0 + kb);
    const float4* w1p = (const float4*)(w_ih + (size_t)(j + 512) * xK + t0 + kb);
    const float4* w2p = (const float4*)(w_ih + (size_t)(j + 1024) * xK + t0 + kb);
    const float* xr = xsh + b * 257 + kb;
#pragma unroll
    for (int k4 = 0; k4 < 8; k4++) {
      float4 wa = w0p[k4], wb = w1p[k4], wc = w2p[k4];
      float xv0 = xr[k4 * 4 + 0], xv1 = xr[k4 * 4 + 1];
      float xv2 = xr[k4 * 4 + 2], xv3 = xr[k4 * 4 + 3];
      gr = fmaf(wa.x, xv0, gr); gr = fmaf(wa.y, xv1, gr);
      gr = fmaf(wa.z, xv2, gr); gr = fmaf(wa.w, xv3, gr);
      gz = fmaf(wb.x, xv0, gz); gz = fmaf(wb.y, xv1, gz);
      gz = fmaf(wb.z, xv2, gz); gz = fmaf(wb.w, xv3, gz);
      gin = fmaf(wc.x, xv0, gin); gin = fmaf(wc.y, xv1, gin);
      gin = fmaf(wc.z, xv2, gin); gin = fmaf(wc.w, xv3, gin);
    }
  }
  for (int t0 = 0; t0 < 512; t0 += 256) {
    __syncthreads();
#pragma unroll
    for (int u = 0; u < 16; u++) {
      int idx = u * 512 + tid;
      xsh[(idx >> 8) * 257 + (idx & 255)] =
          hprev[(size_t)(idx >> 8) * 512 + t0 + (idx & 255)];
    }
    __syncthreads();
    const float4* w0p = (const float4*)(w_hh + (size_t)j * 512 + t0 + kb);
    const float4* w1p = (const float4*)(w_hh + (size_t)(j + 512) * 512 + t0 + kb);
    const float4* w2p = (const float4*)(w_hh + (size_t)(j + 1024) * 512 + t0 + kb);
    const float* xr = xsh + b * 257 + kb;
#pragma unroll
    for (int k4 = 0; k4 < 8; k4++) {
      float4 wa = w0p[k4], wb = w1p[k4], wc = w2p[k4];
      float xv0 = xr[k4 * 4 + 0], xv1 = xr[k4 * 4 + 1];
      float xv2 = xr[k4 * 4 + 2], xv3 = xr[k4 * 4 + 3];
      gr = fmaf(wa.x, xv0, gr); gr = fmaf(wa.y, xv1, gr);
      gr = fmaf(wa.z, xv2, gr); gr = fmaf(wa.w, xv3, gr);
      gz = fmaf(wb.x, xv0, gz); gz = fmaf(wb.y, xv1, gz);
      gz = fmaf(wb.z, xv2, gz); gz = fmaf(wb.w, xv3, gz);
      ghn = fmaf(wc.x, xv0, ghn); ghn = fmaf(wc.y, xv1, ghn);
      ghn = fmaf(wc.z, xv2, ghn); ghn = fmaf(wc.w, xv3, ghn);
    }
  }
  red[tid * 4 + 0] = gr;
  red[tid * 4 + 1] = gz;
  red[tid * 4 + 2] = gin;
  red[tid * 4 + 3] = ghn;
  __syncthreads();
  if (tid < 64) {  // tid = jl*32 + b owns (j = w*2+jl, batch b); sums 8 kq
#pragma unroll
    for (int g = 1; g < 8; g++) {
      gr += red[(tid + g * 64) * 4 + 0];
      gz += red[(tid + g * 64) * 4 + 1];
      gin += red[(tid + g * 64) * 4 + 2];
      ghn += red[(tid + g * 64) * 4 + 3];
    }
    gr += b_ih[j] + b_hh[j];
    gz += b_ih[j + 512] + b_hh[j + 512];
    gin += b_ih[j + 1024];
    ghn += b_hh[j + 1024];
    float r = 1.f / (1.f + __expf(-gr));
    float zz = 1.f / (1.f + __expf(-gz));
    float nv = gin + r * ghn;
    float e2 = __expf(-2.f * fabsf(nv));
    float th = (1.f - e2) / (1.f + e2);
    th = copysignf(th, nv);
    float hp = hprev[b * 512 + j];  // staged this step -> fresh in L1/L2
    float hn = (1.f - zz) * th + zz * hp;
    st_f32_coh(hout + b * 512 + j, hn);
    if (states) states[(size_t)(srow + b) * 1536 + j] = f2bf(hn);
  }
}

// Persistent kernel: prologue + all 63 decode steps in ONE launch.
// grid=256 wgs x 512 thr. Deadlock-proofing: VGPR<=128 (LB(512,4)) + 44KB LDS
// -> per-CU capacity 2 blocks -> total capacity 512 >= grid 256, so ALL blocks
// are resident under ANY dispatch packing (round-4 lesson: zero slack hangs).
__global__ __launch_bounds__(512, 4) void k_steps(StepParams p) {
  __shared__ float xsh[32 * 257];  // 32.9 KB: gru stage; reused as encwt esh
  __shared__ float red[2048];      // 8 KB: gru 8-way partials / attn partials
  __shared__ float h1sh[512];
  __shared__ float ssh[128];
  __shared__ float red2[128];
  int tid = threadIdx.x;
  int w = blockIdx.x;

  // ---------------- prologue (init h slot 0, enc->bf16, encwt) --------------
  {
    int idx = w * 512 + tid;
    if (idx < 16384) st_f32_coh(p.h0buf + idx, p.hidden[idx]);
    else if (idx < 32768) st_f32_coh(p.h1buf + (idx - 16384), p.hidden[idx]);
#pragma unroll
    for (int r = 0; r < 8; r++) {
      size_t i4 = (size_t)r * 131072 + idx;
      float4 v = *(const float4*)(p.enc + i4 * 4);
      ushort4 o;
      o.x = f2bf(v.x); o.y = f2bf(v.y); o.z = f2bf(v.z); o.w = f2bf(v.w);
      union { ushort4 u; i32x2 d; } cv;
      cv.u = o;
      st_b64_coh(p.encb + i4 * 4, cv.d);
    }
    // encwt (TRANSPOSED [b][s][h]): this wg does virtual blocks w and w+256
    for (int blk = w; blk < 512; blk += 256) {
      int b = blk >> 4, s0 = (blk & 15) * 8;
      __syncthreads();
#pragma unroll
      for (int u = 0; u < 16; u++) {
        int f = u * 512 + tid;
        xsh[f] = p.enc[((size_t)b * 128 + s0 + (f >> 10)) * 1024 + (f & 1023)];
      }
      __syncthreads();
      float acc[8] = {};  // this thread owns h = tid for all 8 s-rows
      for (int e = 0; e < 1024; e++) {
        float w0 = p.Wa[e * 512 + tid];
#pragma unroll
        for (int si = 0; si < 8; si++) acc[si] += w0 * xsh[si * 1024 + e];
      }
#pragma unroll
      for (int si = 0; si < 8; si++)
        st_u16_coh(p.encwt + ((size_t)b * 128 + s0 + si) * 512 + tid, f2bf(acc[si]));
    }
  }
  unsigned int* bar = p.bars;
  gbar(bar++);

  // XCD-aware roles: wg->XCD is w%8; each XCD serves 4 whole batches so its L2
  // working set (encwt 512K + encb 1M + weight rows ~2.4M) ~ fits in 4 MB.
  int xcd = w & 7, loc = w >> 3;
  int ab = xcd * 4 + (loc >> 3);  // batch
  int ec = loc & 7;               // e/emb chunk
  for (int t = 0; t < 63; t++) {
    const float* h1prev = p.h1buf + (size_t)t * 16384;
    float* x0t = p.x0b + (size_t)t * 49152;
    // ---------------- Phase A: attention ----------------
    h1sh[tid] = h1prev[ab * 512 + tid];
    __syncthreads();
    {  // scores: 4 threads per s (128-h slices), bf16x8 loads from encwt
      int s = tid & 127, part = tid >> 7;  // part in [0,4)
      const unsigned short* ew = p.encwt + ((size_t)ab * 128 + s) * 512 + part * 128;
      const float* hh = h1sh + part * 128;
      float pacc = 0.f;
#pragma unroll
      for (int hc = 0; hc < 16; hc++) {
        bf16x8 v = *(const bf16x8*)(ew + hc * 8);
        const float* h8 = hh + hc * 8;
        pacc += bf2f((unsigned short)v[0]) * h8[0] + bf2f((unsigned short)v[1]) * h8[1]
              + bf2f((unsigned short)v[2]) * h8[2] + bf2f((unsigned short)v[3]) * h8[3]
              + bf2f((unsigned short)v[4]) * h8[4] + bf2f((unsigned short)v[5]) * h8[5]
              + bf2f((unsigned short)v[6]) * h8[6] + bf2f((unsigned short)v[7]) * h8[7];
      }
      red[tid] = pacc;
    }
    __syncthreads();
    if (tid < 128) {
      float sc = red[tid] + red[tid + 128] + red[tid + 256] + red[tid + 384];
      sc *= 0.03125f;  // 1/sqrt(1024)
      if (p.mask[ab * 128 + tid] == 0) sc = -__builtin_huge_valf();
      ssh[tid] = sc;
      red2[tid] = sc;
    }
    __syncthreads();
    for (int st = 64; st > 0; st >>= 1) {
      if (tid < st) red2[tid] = fmaxf(red2[tid], red2[tid + st]);
      __syncthreads();
    }
    float mx = red2[0];
    __syncthreads();
    if (tid < 128) {
      float e = __expf(ssh[tid] - mx);
      ssh[tid] = e;
      red2[tid] = e;
    }
    __syncthreads();
    for (int st = 64; st > 0; st >>= 1) {
      if (tid < st) red2[tid] += red2[tid + st];
      __syncthreads();
    }
    float inv = 1.f / red2[0];
    __syncthreads();
    if (tid < 128) ssh[tid] *= inv;
    __syncthreads();
    {  // ctx for this wg's 128-wide e-chunk (4 threads per e, 32-s slices)
      int el = tid & 127, sh_ = tid >> 7;
      const unsigned short* eb = p.encb + (size_t)ab * 131072 + ec * 128 + el;
      int sbase = sh_ * 32;
      float c = 0.f;
#pragma unroll 8
      for (int s2 = 0; s2 < 32; s2++)
        c += ssh[sbase + s2] * bf2f(eb[(size_t)(sbase + s2) * 1024]);
      red[tid] = c;
    }
    __syncthreads();
    if (tid < 128) {
      float cv = red[tid] + red[tid + 128] + red[tid + 256] + red[tid + 384];
      st_f32_coh(x0t + ab * 1536 + 512 + ec * 128 + tid, cv);
      p.states[(size_t)(t * 32 + ab) * 1536 + 512 + ec * 128 + tid] = f2bf(cv);
    }
    {  // embedding gather: this wg's 64-wide chunk
      int tok = p.tgt[ab * 64 + t];
      if (tid < 64)
        st_f32_coh(x0t + ab * 1536 + ec * 64 + tid,
                   p.embedding[(size_t)tok * 512 + ec * 64 + tid]);
    }
    gbar(bar++);
    // ---------------- Phase B: GRU layer 0 ----------------
    gru_phase(x0t, 1536, p.h0buf + (size_t)t * 16384, p.w_ih0, p.w_hh0, p.b_ih0,
              p.b_hh0, p.h0buf + (size_t)(t + 1) * 16384,
              (unsigned short*)nullptr, 0, w, tid, xsh, red);
    gbar(bar++);
    // ---------------- Phase C: GRU layer 1 ----------------
    gru_phase(p.h0buf + (size_t)(t + 1) * 16384, 512, p.h1buf + (size_t)t * 16384,
              p.w_ih1, p.w_hh1, p.b_ih1, p.b_hh1,
              p.h1buf + (size_t)(t + 1) * 16384, p.states, t * 32, w, tid, xsh, red);
    gbar(bar++);
  }
}

// ---------------- fc_w fp32 -> bf16 one-time convert (guarded on ws_size) ---
__global__ __launch_bounds__(256) void k_cvt_fcw(const float* __restrict__ w,
                                                 unsigned short* __restrict__ o) {
  size_t i = ((size_t)blockIdx.x * 256 + threadIdx.x) * 8;
  float4 a = *(const float4*)(w + i);
  float4 b = *(const float4*)(w + i + 4);
  ushort4 lo, hi;
  lo.x = f2bf(a.x); lo.y = f2bf(a.y); lo.z = f2bf(a.z); lo.w = f2bf(a.w);
  hi.x = f2bf(b.x); hi.y = f2bf(b.y); hi.z = f2bf(b.z); hi.w = f2bf(b.w);
  *(ushort4*)(o + i) = lo;
  *(ushort4*)(o + i + 4) = hi;
}

// ---------------- batched logits GEMM: [2016x1536] @ fc_w.T [1536x32000] ----
// XCD-swizzled: the 16 m-blocks sharing one B-panel land on one XCD's L2.
template <bool PRE>
__global__ __launch_bounds__(256) void k_gemm(
    const unsigned short* __restrict__ states,  // [2048][1536] bf16
    const float* __restrict__ fc_w,             // [32000][1536]
    const unsigned short* __restrict__ fcwb,    // [32000][1536] bf16 (PRE only)
    const float* __restrict__ fc_b,             // [32000]
    float* __restrict__ out) {                  // [32][63][32000]
  __shared__ unsigned short Ash[128 * 40];
  __shared__ unsigned short Bsh[128 * 40];
  int tid = threadIdx.x;
  int bx = blockIdx.x;
  int bid = (bx & 7) * 500 + (bx >> 3);  // 4000 = 8 XCDs * 500, bijective
  int m0 = (bid & 15) * 128;
  int n0 = (bid >> 4) * 128;
  int lane = tid & 63, wave = tid >> 6;
  int q = lane >> 4, l16 = lane & 15;
  int wrow = (wave >> 1) * 64, wcol = (wave & 1) * 64;
  int arow = tid >> 1, ahalf = tid & 1;
  f32x4 acc[4][4] = {};
  const unsigned short* ag = states + (size_t)(m0 + arow) * 1536 + ahalf * 16;
  const float* bg = fc_w + (size_t)(n0 + arow) * 1536 + ahalf * 16;
  const unsigned short* bgb = PRE ? fcwb + (size_t)(n0 + arow) * 1536 + ahalf * 16 : nullptr;
  for (int k0 = 0; k0 < 1536; k0 += 32) {
    {  // stage A (already bf16)
      const int4* src = (const int4*)(ag + k0);
      int4* dst = (int4*)(Ash + arow * 40 + ahalf * 16);
      dst[0] = src[0];
      dst[1] = src[1];
    }
    if constexpr (PRE) {  // stage B (pre-converted bf16)
      const int4* src = (const int4*)(bgb + k0);
      int4* dst = (int4*)(Bsh + arow * 40 + ahalf * 16);
      dst[0] = src[0];
      dst[1] = src[1];
    } else {  // stage B (fp32 -> bf16)
      const float4* src = (const float4*)(bg + k0);
      __align__(16) unsigned short us[16];
#pragma unroll
      for (int i = 0; i < 4; i++) {
        float4 v = src[i];
        us[i * 4 + 0] = f2bf(v.x);
        us[i * 4 + 1] = f2bf(v.y);
        us[i * 4 + 2] = f2bf(v.z);
        us[i * 4 + 3] = f2bf(v.w);
      }
      int4* dst = (int4*)(Bsh + arow * 40 + ahalf * 16);
      dst[0] = ((int4*)us)[0];
      dst[1] = ((int4*)us)[1];
    }
    __syncthreads();
    bf16x8 av[4], bv[4];
#pragma unroll
    for (int i = 0; i < 4; i++) {
      av[i] = *(const bf16x8*)(Ash + (wrow + i * 16 + l16) * 40 + q * 8);
      bv[i] = *(const bf16x8*)(Bsh + (wcol + i * 16 + l16) * 40 + q * 8);
    }
#pragma unroll
    for (int mi = 0; mi < 4; mi++)
#pragma unroll
      for (int ni = 0; ni < 4; ni++)
        acc[mi][ni] = __builtin_amdgcn_mfma_f32_16x16x32_bf16(av[mi], bv[ni], acc[mi][ni], 0, 0, 0);
    __syncthreads();
  }
  float fb[4];
#pragma unroll
  for (int ni = 0; ni < 4; ni++) fb[ni] = fc_b[n0 + wcol + ni * 16 + l16];
#pragma unroll
  for (int mi = 0; mi < 4; mi++) {
#pragma unroll
    for (int r = 0; r < 4; r++) {
      int grow = m0 + wrow + mi * 16 + q * 4 + r;
      if (grow < 2016) {
        int tt = grow >> 5, bb = grow & 31;
        float* op = out + (size_t)bb * 2016000 + (size_t)tt * 32000 + n0 + wcol;
#pragma unroll
        for (int ni = 0; ni < 4; ni++)
          op[ni * 16 + l16] = acc[mi][ni][r] + fb[ni];
      }
    }
  }
}

extern "C" void kernel_launch(void* const* d_in, const int* in_sizes, int n_in,
                              void* d_out, int out_size, void* d_ws, size_t ws_size,
                              hipStream_t stream) {
  const int* tgt = (const int*)d_in[0];
  const float* hidden = (const float*)d_in[1];
  const float* enc = (const float*)d_in[2];
  const int* mask = (const int*)d_in[3];
  const float* embedding = (const float*)d_in[4];
  const float* Wa = (const float*)d_in[5];
  const float* w_ih0 = (const float*)d_in[6];
  const float* w_hh0 = (const float*)d_in[7];
  const float* b_ih0 = (const float*)d_in[8];
  const float* b_hh0 = (const float*)d_in[9];
  const float* w_ih1 = (const float*)d_in[10];
  const float* w_hh1 = (const float*)d_in[11];
  const float* b_ih1 = (const float*)d_in[12];
  const float* b_hh1 = (const float*)d_in[13];
  const float* fc_w = (const float*)d_in[14];
  const float* fc_b = (const float*)d_in[15];
  float* out = (float*)d_out;
  char* ws = (char*)d_ws;

  float* h0buf = (float*)(ws + 0);                           // [64][32][512] f32 slots
  float* h1buf = (float*)(ws + 4194304);                     // [64][32][512] f32 slots
  float* x0b = (float*)(ws + 8388608);                       // [63][32][1536] f32 slots
  unsigned short* encb = (unsigned short*)(ws + 20774912);   // [32][128][1024] bf16
  unsigned short* encwt = (unsigned short*)(ws + 29163520);  // [32][128][512] bf16
  unsigned short* states = (unsigned short*)(ws + 33357824); // [2048][1536] bf16
  unsigned int* bars = (unsigned int*)(ws + 39649280);       // 190 counters
  const size_t FCWB_OFF = 41943040ull;
  unsigned short* fcwb = (unsigned short*)(ws + FCWB_OFF);   // [32000][1536] bf16
  bool pre = ws_size >= FCWB_OFF + 98304000ull;

  hipMemsetAsync(bars, 0, 4096, stream);
  if (pre) k_cvt_fcw<<<24000, 256, 0, stream>>>(fc_w, fcwb);

  StepParams p;
  p.tgt = tgt; p.mask = mask; p.embedding = embedding; p.enc = enc; p.Wa = Wa;
  p.hidden = hidden;
  p.w_ih0 = w_ih0; p.w_hh0 = w_hh0; p.b_ih0 = b_ih0; p.b_hh0 = b_hh0;
  p.w_ih1 = w_ih1; p.w_hh1 = w_hh1; p.b_ih1 = b_ih1; p.b_hh1 = b_hh1;
  p.h0buf = h0buf; p.h1buf = h1buf; p.x0b = x0b;
  p.encb = encb; p.encwt = encwt; p.states = states; p.bars = bars;

  k_steps<<<dim3(256), dim3(512), 0, stream>>>(p);

  if (pre) k_gemm<true><<<4000, 256, 0, stream>>>(states, fc_w, fcwb, fc_b, out);
  else k_gemm<false><<<4000, 256, 0, stream>>>(states, fc_w, nullptr, fc_b, out);
}